// Round 1
// baseline (133.429 us; speedup 1.0000x reference)
//
#include <hip/hip_runtime.h>
#include <math.h>

#define BROWS 512
#define SLEN  8192
#define NT    512              // threads per block
#define CHUNK (SLEN / NT)      // 16 positions per thread
#define NWRD  (SLEN / 32)      // 256 mask words per row
#define MWRD  (NWRD + 2)       // +2 guard words (one each side)

// distance (capped; >5 -> 99) to nearest set bit within +/-5 of position t
__device__ __forceinline__ int win_dist(const unsigned int* __restrict__ M, int t) {
    int sI = t + 27;                   // (t-5) + 32-bit guard offset
    int w  = sI >> 5;
    int off = sI & 31;
    unsigned long long val =
        ((unsigned long long)M[w] | ((unsigned long long)M[w + 1] << 32)) >> off;
    unsigned int win = (unsigned int)val & 0x7FFu;   // bit5 == position t
    if (win & 32u) return 0;
    unsigned int dn = win & 31u;          // bits 0..4 = t-5..t-1 (bit i -> dist 5-i)
    unsigned int up = (win >> 6) & 31u;   // bits 0..4 = t+1..t+5 (bit j -> dist j+1)
    int d = 99;
    if (dn) d = 5 - (31 - __clz((int)dn));
    if (up) { int du = __ffs((int)up); if (du < d) d = du; }
    return d;
}

__device__ __forceinline__ float decay_pow(int d) {
    // 0.7^d for d in 1..5
    return (d == 1) ? 0.7f : (d == 2) ? 0.49f : (d == 3) ? 0.343f
         : (d == 4) ? 0.2401f : 0.16807f;
}

__global__ __launch_bounds__(NT) void row_loss_kernel(
    const float* __restrict__ logits, const int* __restrict__ labels,
    double* __restrict__ ws_sum, unsigned int* __restrict__ ws_cnt)
{
    __shared__ float         s_ce[SLEN];        // 32 KB
    __shared__ unsigned char s_pk[SLEN];        // 8 KB   pred(2b)|lab(2b)|valid(1b)
    __shared__ unsigned int  s_m[4][MWRD];      // ~4.1 KB  masks: t2, p2, t3, p3
    __shared__ unsigned int  s_scan[NT];        // 2 KB
    __shared__ unsigned int  s_flags;           // hasT2|hasP2|hasT3|hasP3
    __shared__ double        s_red[NT / 64];
    __shared__ unsigned int  s_redc[NT / 64];

    const int row = blockIdx.x;
    const int tid = threadIdx.x;

    for (int i = tid; i < 4 * MWRD; i += NT) ((unsigned int*)s_m)[i] = 0u;
    if (tid == 0) s_flags = 0u;
    __syncthreads();

    const float4* lg4 = (const float4*)(logits + (size_t)row * SLEN * 4);
    const int*    lb  = labels + (size_t)row * SLEN;

    // ---- Phase 1: coalesced load, argmax + weighted CE, pack to LDS ----
    for (int k = 0; k < CHUNK; ++k) {
        int t = k * NT + tid;
        float4 v = lg4[t];
        int lab = lb[t];
        int pred = 0; float best = v.x;
        if (v.y > best) { best = v.y; pred = 1; }
        if (v.z > best) { best = v.z; pred = 2; }
        if (v.w > best) { best = v.w; pred = 3; }
        bool valid = (lab != -100);
        int l = valid ? (lab & 3) : 0;
        float se = __expf(v.x - best) + __expf(v.y - best) +
                   __expf(v.z - best) + __expf(v.w - best);
        float lse = best + __logf(se);
        float xl = (l == 0) ? v.x : (l == 1) ? v.y : (l == 2) ? v.z : v.w;
        float wc = (l >= 2) ? 30.0f : 1.0f;
        s_ce[t] = valid ? (lse - xl) * wc : 0.0f;
        s_pk[t] = (unsigned char)(pred | (l << 2) | (valid ? 16 : 0));
    }
    __syncthreads();

    // ---- Phase 2: per-chunk masks + mode-scan summary ----
    const int base = tid * CHUNK;
    unsigned int mt2 = 0, mp2 = 0, mt3 = 0, mp3 = 0;
    unsigned int summary = 0;   // bit0 pm, bit1 tm, bit2 any_valid
    for (int i = 0; i < CHUNK; ++i) {
        unsigned int pk = s_pk[base + i];
        int pred = pk & 3, l = (pk >> 2) & 3;
        bool valid = (pk & 16) != 0;
        if (pred == 2) mp2 |= 1u << i;
        if (pred == 3) mp3 |= 1u << i;
        if (valid && l == 2) mt2 |= 1u << i;
        if (valid && l == 3) mt3 |= 1u << i;
        if (valid) summary = 4u | (unsigned)(pred & 1) | ((unsigned)(l & 1) << 1);
    }
    {
        int wi = 1 + (tid >> 1);
        int sh = (tid & 1) * 16;
        if (mt2) atomicOr(&s_m[0][wi], mt2 << sh);
        if (mp2) atomicOr(&s_m[1][wi], mp2 << sh);
        if (mt3) atomicOr(&s_m[2][wi], mt3 << sh);
        if (mp3) atomicOr(&s_m[3][wi], mp3 << sh);
        unsigned int fl = (mt2 ? 1u : 0u) | (mp2 ? 2u : 0u) |
                          (mt3 ? 4u : 0u) | (mp3 ? 8u : 0u);
        if (fl) atomicOr(&s_flags, fl);
    }
    s_scan[tid] = summary;
    __syncthreads();

    // Hillis-Steele fill-forward scan over chunk summaries
    for (int step = 1; step < NT; step <<= 1) {
        unsigned int v = s_scan[tid];
        unsigned int o = (tid >= step) ? s_scan[tid - step] : 0u;
        unsigned int nv = (v & 4u) ? v : o;
        __syncthreads();
        s_scan[tid] = nv;
        __syncthreads();
    }

    // ---- Phase 3: replay chunk with carry, window multipliers, accumulate ----
    unsigned int pre = (tid > 0) ? s_scan[tid - 1] : 0u;
    int pm = (int)(pre & 1u), tm = (int)((pre >> 1) & 1u);
    unsigned int flags = s_flags;
    const bool hasT2 = flags & 1u, hasP2 = flags & 2u;
    const bool hasT3 = flags & 4u, hasP3 = flags & 8u;

    float acc = 0.0f;
    int cnt = 0;
    for (int i = 0; i < CHUNK; ++i) {
        int t = base + i;
        unsigned int pk = s_pk[t];
        int pred = pk & 3, l = (pk >> 2) & 3;
        bool valid = (pk & 16) != 0;
        float m = 1.0f;
        if (valid) {
            bool bad = (pred == 2 && pm == 0) || (pred == 3 && pm == 1);
            if (bad) m *= 100.0f;
            bool good = (l == 2 && tm == 1 && pred == 2) ||
                        (l == 3 && tm == 0 && pred == 3);
            if (good) m *= 0.1f;
            pm = pred & 1;
            tm = l & 1;
            cnt++;
        }
        if (pred == 2) {
            if (!hasT2) m *= 20.0f;
            else { int d = win_dist(s_m[0], t);
                   m *= (d == 0) ? 0.1f : (d <= 5) ? decay_pow(d) : 10.0f; }
        }
        if (valid && l == 2) {
            if (!hasP2) m *= 3.0f;
            else if (win_dist(s_m[1], t) > 5) m *= 2.0f;
        }
        if (pred == 3) {
            if (!hasT3) m *= 20.0f;
            else { int d = win_dist(s_m[2], t);
                   m *= (d == 0) ? 0.1f : (d <= 5) ? decay_pow(d) : 10.0f; }
        }
        if (valid && l == 3) {
            if (!hasP3) m *= 3.0f;
            else if (win_dist(s_m[3], t) > 5) m *= 2.0f;
        }
        acc += s_ce[t] * m;
    }

    // ---- Reduce ----
    double dacc = (double)acc;
    for (int o = 32; o > 0; o >>= 1) {
        dacc += __shfl_down(dacc, o);
        cnt  += __shfl_down(cnt, o);
    }
    int wid = tid >> 6, lane = tid & 63;
    if (lane == 0) { s_red[wid] = dacc; s_redc[wid] = (unsigned int)cnt; }
    __syncthreads();
    if (tid == 0) {
        double tot = 0.0; unsigned int c = 0;
        for (int i = 0; i < NT / 64; ++i) { tot += s_red[i]; c += s_redc[i]; }
        atomicAdd(ws_sum, tot);
        atomicAdd(ws_cnt, c);
    }
}

__global__ void finalize_kernel(const double* __restrict__ ws_sum,
                                const unsigned int* __restrict__ ws_cnt,
                                float* __restrict__ out)
{
    double c = (double)(*ws_cnt);
    if (c < 1.0) c = 1.0;
    out[0] = (float)(*ws_sum / c);
}

extern "C" void kernel_launch(void* const* d_in, const int* in_sizes, int n_in,
                              void* d_out, int out_size, void* d_ws, size_t ws_size,
                              hipStream_t stream) {
    const float* logits = (const float*)d_in[0];
    const int*   labels = (const int*)d_in[1];
    float* out = (float*)d_out;
    double* wsd = (double*)d_ws;
    unsigned int* wsc = (unsigned int*)(wsd + 1);

    hipMemsetAsync(d_ws, 0, 16, stream);
    row_loss_kernel<<<BROWS, NT, 0, stream>>>(logits, labels, wsd, wsc);
    finalize_kernel<<<1, 1, 0, stream>>>(wsd, wsc, out);
}

// Round 2
// 115.854 us; speedup vs baseline: 1.1517x; 1.1517x over previous
//
#include <hip/hip_runtime.h>
#include <math.h>

#define BROWS 512
#define SLEN  8192
#define NT    1024             // threads per block (16 waves)
#define CHUNK (SLEN / NT)      // 8 positions per thread
#define NWRD  (SLEN / 32)      // 256 mask words per row
#define MWRD  (NWRD + 2)       // +1 guard word each side
#define CEPAD (SLEN + SLEN/8)  // padded ce layout: idx = t + (t>>3)

// distance (capped; >5 -> 99) to nearest set bit within +/-5 of position t
__device__ __forceinline__ int win_dist(const unsigned int* __restrict__ M, int t) {
    int sI = t + 27;                   // (t-5) + 32-bit guard offset
    int w  = sI >> 5;
    int off = sI & 31;
    unsigned long long val =
        ((unsigned long long)M[w] | ((unsigned long long)M[w + 1] << 32)) >> off;
    unsigned int win = (unsigned int)val & 0x7FFu;   // bit5 == position t
    if (win & 32u) return 0;
    unsigned int dn = win & 31u;          // bits 0..4 = t-5..t-1 (bit i -> dist 5-i)
    unsigned int up = (win >> 6) & 31u;   // bits 0..4 = t+1..t+5 (bit j -> dist j+1)
    int d = 99;
    if (dn) d = 5 - (31 - __clz((int)dn));
    if (up) { int du = __ffs((int)up); if (du < d) d = du; }
    return d;
}

__device__ __forceinline__ float decay_pow(int d) {
    return (d == 1) ? 0.7f : (d == 2) ? 0.49f : (d == 3) ? 0.343f
         : (d == 4) ? 0.2401f : 0.16807f;
}

__global__ __launch_bounds__(NT, 8) void row_loss_kernel(
    const float* __restrict__ logits, const int* __restrict__ labels,
    double* __restrict__ psum, unsigned int* __restrict__ pcnt)
{
    __shared__ float         s_ce[CEPAD];       // 36 KB, padded (stride-9 reads)
    __shared__ unsigned char s_pk[SLEN];        // 8 KB   pred(2b)|lab(2b)|valid(1b)
    __shared__ unsigned int  s_m[4][MWRD];      // ~4.1 KB  masks: t2, p2, t3, p3
    __shared__ unsigned int  s_wave[16];
    __shared__ unsigned int  s_wavex[16];
    __shared__ unsigned int  s_flags;
    __shared__ double        s_red[16];
    __shared__ int           s_redc[16];

    const int row  = blockIdx.x;
    const int tid  = threadIdx.x;
    const int lane = tid & 63;
    const int wid  = tid >> 6;

    for (int i = tid; i < 4 * MWRD; i += NT) ((unsigned int*)s_m)[i] = 0u;
    if (tid == 0) s_flags = 0u;

    const float4* lg4 = (const float4*)(logits + (size_t)row * SLEN * 4);
    const int*    lb  = labels + (size_t)row * SLEN;

    // ---- Phase 1: coalesced load, argmax + weighted CE, pack to LDS ----
    #pragma unroll
    for (int k = 0; k < CHUNK; ++k) {
        int t = k * NT + tid;
        float4 v = lg4[t];
        int lab = lb[t];
        int pred = 0; float best = v.x;
        if (v.y > best) { best = v.y; pred = 1; }
        if (v.z > best) { best = v.z; pred = 2; }
        if (v.w > best) { best = v.w; pred = 3; }
        bool valid = (lab != -100);
        int l = valid ? (lab & 3) : 0;
        float se = __expf(v.x - best) + __expf(v.y - best) +
                   __expf(v.z - best) + __expf(v.w - best);
        float lse = best + __logf(se);
        float xl = (l == 0) ? v.x : (l == 1) ? v.y : (l == 2) ? v.z : v.w;
        float wc = (l >= 2) ? 30.0f : 1.0f;
        s_ce[t + (t >> 3)] = valid ? (lse - xl) * wc : 0.0f;
        s_pk[t] = (unsigned char)(pred | (l << 2) | (valid ? 16 : 0));
    }
    __syncthreads();   // A: s_pk/s_ce/s_m-zero visible

    // ---- Phase 2: per-chunk masks + mode-scan summary ----
    const int base = tid * CHUNK;
    unsigned int mt2 = 0, mp2 = 0, mt3 = 0, mp3 = 0;
    unsigned int summary = 0;   // bit0 pm, bit1 tm, bit2 any_valid
    #pragma unroll
    for (int i = 0; i < CHUNK; ++i) {
        unsigned int pk = s_pk[base + i];
        int pred = pk & 3, l = (pk >> 2) & 3;
        bool valid = (pk & 16) != 0;
        if (pred == 2) mp2 |= 1u << i;
        if (pred == 3) mp3 |= 1u << i;
        if (valid && l == 2) mt2 |= 1u << i;
        if (valid && l == 3) mt3 |= 1u << i;
        if (valid) summary = 4u | (unsigned)(pred & 1) | ((unsigned)(l & 1) << 1);
    }
    {   // masks: global bit = 32(guard) + tid*8 + i  ->  word 1 + tid/4, shift (tid&3)*8
        int wi = 1 + (tid >> 2);
        int sh = (tid & 3) * 8;
        if (mt2) atomicOr(&s_m[0][wi], mt2 << sh);
        if (mp2) atomicOr(&s_m[1][wi], mp2 << sh);
        if (mt3) atomicOr(&s_m[2][wi], mt3 << sh);
        if (mp3) atomicOr(&s_m[3][wi], mp3 << sh);
    }
    {   // row-wide has-any flags: wave OR-reduce, one LDS atomic per wave
        unsigned int fl = (mt2 ? 1u : 0u) | (mp2 ? 2u : 0u) |
                          (mt3 ? 4u : 0u) | (mp3 ? 8u : 0u);
        #pragma unroll
        for (int s = 32; s > 0; s >>= 1) fl |= __shfl_xor(fl, s);
        if (lane == 0 && fl) atomicOr(&s_flags, fl);
    }

    // ---- fill-forward scan over chunk summaries (shuffle, 2 barriers) ----
    unsigned int inc = summary;
    #pragma unroll
    for (int st = 1; st < 64; st <<= 1) {
        unsigned int o = __shfl_up(inc, st);
        if (lane >= st && !(inc & 4u)) inc = o;
    }
    unsigned int exc = __shfl_up(inc, 1);
    if (lane == 0) exc = 0u;
    if (lane == 63) s_wave[wid] = inc;
    __syncthreads();   // B: s_wave + s_m atomics + s_flags visible
    if (wid == 0) {
        unsigned int wv = (lane < 16) ? s_wave[lane] : 0u;
        #pragma unroll
        for (int st = 1; st < 16; st <<= 1) {
            unsigned int o = __shfl_up(wv, st);
            if (lane >= st && !(wv & 4u)) wv = o;
        }
        unsigned int wex = __shfl_up(wv, 1);
        if (lane == 0) wex = 0u;
        if (lane < 16) s_wavex[lane] = wex;
    }
    __syncthreads();   // C

    unsigned int pre = (exc & 4u) ? exc : s_wavex[wid];
    int pm = (int)(pre & 1u), tm = (int)((pre >> 1) & 1u);
    unsigned int flags = s_flags;
    const bool hasT2 = flags & 1u, hasP2 = flags & 2u;
    const bool hasT3 = flags & 4u, hasP3 = flags & 8u;

    // ---- Phase 3: replay chunk with carry, window multipliers, accumulate ----
    float acc = 0.0f;
    int cnt = 0;
    #pragma unroll
    for (int i = 0; i < CHUNK; ++i) {
        int t = base + i;
        unsigned int pk = s_pk[t];
        int pred = pk & 3, l = (pk >> 2) & 3;
        bool valid = (pk & 16) != 0;
        float m = 1.0f;
        if (valid) {
            bool bad = (pred == 2 && pm == 0) || (pred == 3 && pm == 1);
            if (bad) m *= 100.0f;
            bool good = (l == 2 && tm == 1 && pred == 2) ||
                        (l == 3 && tm == 0 && pred == 3);
            if (good) m *= 0.1f;
            pm = pred & 1;
            tm = l & 1;
            cnt++;
        }
        if (pred == 2) {
            if (!hasT2) m *= 20.0f;
            else { int d = win_dist(s_m[0], t);
                   m *= (d == 0) ? 0.1f : (d <= 5) ? decay_pow(d) : 10.0f; }
        }
        if (valid && l == 2) {
            if (!hasP2) m *= 3.0f;
            else if (win_dist(s_m[1], t) > 5) m *= 2.0f;
        }
        if (pred == 3) {
            if (!hasT3) m *= 20.0f;
            else { int d = win_dist(s_m[2], t);
                   m *= (d == 0) ? 0.1f : (d <= 5) ? decay_pow(d) : 10.0f; }
        }
        if (valid && l == 3) {
            if (!hasP3) m *= 3.0f;
            else if (win_dist(s_m[3], t) > 5) m *= 2.0f;
        }
        acc += s_ce[tid * 9 + i] * m;   // padded: t + (t>>3) == tid*9+i
    }

    // ---- Reduce to per-row partial (no global atomics, no ws init needed) ----
    double dacc = (double)acc;
    #pragma unroll
    for (int o = 32; o > 0; o >>= 1) {
        dacc += __shfl_down(dacc, o);
        cnt  += __shfl_down(cnt, o);
    }
    if (lane == 0) { s_red[wid] = dacc; s_redc[wid] = cnt; }
    __syncthreads();   // D
    if (tid == 0) {
        double tot = 0.0; unsigned int c = 0;
        #pragma unroll
        for (int i = 0; i < 16; ++i) { tot += s_red[i]; c += (unsigned int)s_redc[i]; }
        psum[row] = tot;
        pcnt[row] = c;
    }
}

__global__ __launch_bounds__(512) void finalize_kernel(
    const double* __restrict__ psum, const unsigned int* __restrict__ pcnt,
    float* __restrict__ out)
{
    __shared__ double       sd[8];
    __shared__ unsigned int sc[8];
    int tid = threadIdx.x, lane = tid & 63, wid = tid >> 6;
    double v = psum[tid];
    unsigned int c = pcnt[tid];
    #pragma unroll
    for (int o = 32; o > 0; o >>= 1) {
        v += __shfl_down(v, o);
        c += __shfl_down(c, o);
    }
    if (lane == 0) { sd[wid] = v; sc[wid] = c; }
    __syncthreads();
    if (tid == 0) {
        double t = 0.0; unsigned int cc = 0;
        #pragma unroll
        for (int i = 0; i < 8; ++i) { t += sd[i]; cc += sc[i]; }
        double d = (cc > 0u) ? (double)cc : 1.0;
        out[0] = (float)(t / d);
    }
}

extern "C" void kernel_launch(void* const* d_in, const int* in_sizes, int n_in,
                              void* d_out, int out_size, void* d_ws, size_t ws_size,
                              hipStream_t stream) {
    const float* logits = (const float*)d_in[0];
    const int*   labels = (const int*)d_in[1];
    float* out = (float*)d_out;
    double* psum = (double*)d_ws;
    unsigned int* pcnt = (unsigned int*)(psum + BROWS);

    row_loss_kernel<<<BROWS, NT, 0, stream>>>(logits, labels, psum, pcnt);
    finalize_kernel<<<1, 512, 0, stream>>>(psum, pcnt, out);
}

// Round 3
// 113.028 us; speedup vs baseline: 1.1805x; 1.0250x over previous
//
#include <hip/hip_runtime.h>
#include <math.h>

#define BROWS 512
#define SLEN  8192
#define NT    1024             // threads per block (16 waves)
#define CHUNK (SLEN / NT)      // 8 positions per thread
#define NWRD  (SLEN / 32)      // 256 mask words per row
#define MWRD  (NWRD + 2)       // +1 guard word each side

// distance (capped; >5 -> 99) to nearest set bit within +/-5 of position t
__device__ __forceinline__ int win_dist(const unsigned int* __restrict__ M, int t) {
    int sI = t + 27;                   // (t-5) + 32-bit guard offset
    int w  = sI >> 5;
    int off = sI & 31;
    unsigned long long val =
        ((unsigned long long)M[w] | ((unsigned long long)M[w + 1] << 32)) >> off;
    unsigned int win = (unsigned int)val & 0x7FFu;   // bit5 == position t
    if (win & 32u) return 0;
    unsigned int dn = win & 31u;          // bits 0..4 = t-5..t-1 (bit i -> dist 5-i)
    unsigned int up = (win >> 6) & 31u;   // bits 0..4 = t+1..t+5 (bit j -> dist j+1)
    int d = 99;
    if (dn) d = 5 - (31 - __clz((int)dn));
    if (up) { int du = __ffs((int)up); if (du < d) d = du; }
    return d;
}

__device__ __forceinline__ float decay_pow(int d) {
    return (d == 1) ? 0.7f : (d == 2) ? 0.49f : (d == 3) ? 0.343f
         : (d == 4) ? 0.2401f : 0.16807f;
}

__global__ __launch_bounds__(NT, 8) void row_loss_kernel(
    const float* __restrict__ logits, const int* __restrict__ labels,
    double* __restrict__ psum, unsigned int* __restrict__ pcnt)
{
    __shared__ float         s_ce[SLEN];        // 32 KB (b128 reads in phase 3)
    __shared__ unsigned char s_pk[SLEN];        // 8 KB   pred(2b)|lab(2b)|valid(1b)
    __shared__ unsigned int  s_m[4][MWRD];      // ~4.1 KB  masks: t2, p2, t3, p3
    __shared__ unsigned int  s_wave[16];
    __shared__ unsigned int  s_wavex[16];
    __shared__ unsigned int  s_flags;
    __shared__ double        s_red[16];
    __shared__ int           s_redc[16];

    const int row  = blockIdx.x;
    const int tid  = threadIdx.x;
    const int lane = tid & 63;
    const int wid  = tid >> 6;

    // only guard words need zeroing (interior fully written in phase 2)
    if (tid < 8) s_m[tid >> 1][(tid & 1) ? (MWRD - 1) : 0] = 0u;
    if (tid == 0) s_flags = 0u;

    const float4* lg4 = (const float4*)(logits + (size_t)row * SLEN * 4);
    const int*    lb  = labels + (size_t)row * SLEN;

    // ---- Phase 1: batched coalesced loads, argmax + weighted CE -> LDS ----
    int cnt = 0;
    #pragma unroll
    for (int kk = 0; kk < CHUNK; kk += 4) {
        float4 v[4]; int la[4];
        #pragma unroll
        for (int j = 0; j < 4; ++j) {
            int t = (kk + j) * NT + tid;
            v[j]  = lg4[t];
            la[j] = lb[t];
        }
        #pragma unroll
        for (int j = 0; j < 4; ++j) {
            int t = (kk + j) * NT + tid;
            float4 q = v[j];
            int lab  = la[j];
            float m01 = fmaxf(q.x, q.y), m23 = fmaxf(q.z, q.w);
            float best = fmaxf(m01, m23);
            int pred = (best == q.x) ? 0 : (best == q.y) ? 1 : (best == q.z) ? 2 : 3;
            bool valid = (lab != -100);
            cnt += valid ? 1 : 0;
            int l = valid ? (lab & 3) : 0;
            float se = __expf(q.x - best) + __expf(q.y - best) +
                       __expf(q.z - best) + __expf(q.w - best);
            float lse = best + __logf(se);
            float xl = (l == 0) ? q.x : (l == 1) ? q.y : (l == 2) ? q.z : q.w;
            float wc = (l >= 2) ? 30.0f : 1.0f;
            s_ce[t] = valid ? (lse - xl) * wc : 0.0f;
            s_pk[t] = (unsigned char)(pred | (l << 2) | (valid ? 16 : 0));
        }
    }
    __syncthreads();   // A

    // ---- Phase 2: per-chunk masks + mode-scan summary (one b64 pk read) ----
    const int base = tid * CHUNK;
    const unsigned long long pkw = *(const unsigned long long*)(s_pk + base);
    unsigned int mt2 = 0, mp2 = 0, mt3 = 0, mp3 = 0;
    unsigned int summary = 0;   // bit0 pm, bit1 tm, bit2 any_valid
    #pragma unroll
    for (int i = 0; i < CHUNK; ++i) {
        unsigned int pk = (unsigned int)(pkw >> (8 * i)) & 31u;
        int pred = pk & 3, l = (pk >> 2) & 3;
        bool valid = (pk & 16) != 0;
        if (pred == 2) mp2 |= 1u << i;
        if (pred == 3) mp3 |= 1u << i;
        if (valid && l == 2) mt2 |= 1u << i;
        if (valid && l == 3) mt3 |= 1u << i;
        if (valid) summary = 4u | (unsigned)(pred & 1) | ((unsigned)(l & 1) << 1);
    }
    {   // combine 4 lanes' bytes -> one word, single-lane plain write
        int sh = (tid & 3) * 8;
        unsigned int w0 = mt2 << sh, w1 = mp2 << sh, w2 = mt3 << sh, w3 = mp3 << sh;
        w0 |= __shfl_xor(w0, 1); w0 |= __shfl_xor(w0, 2);
        w1 |= __shfl_xor(w1, 1); w1 |= __shfl_xor(w1, 2);
        w2 |= __shfl_xor(w2, 1); w2 |= __shfl_xor(w2, 2);
        w3 |= __shfl_xor(w3, 1); w3 |= __shfl_xor(w3, 2);
        if ((tid & 3) == 0) {
            int wi = 1 + (tid >> 2);
            s_m[0][wi] = w0; s_m[1][wi] = w1; s_m[2][wi] = w2; s_m[3][wi] = w3;
        }
    }
    {   // row-wide has-any flags: wave OR-reduce, one LDS atomic per wave
        unsigned int fl = (mt2 ? 1u : 0u) | (mp2 ? 2u : 0u) |
                          (mt3 ? 4u : 0u) | (mp3 ? 8u : 0u);
        #pragma unroll
        for (int s = 32; s > 0; s >>= 1) fl |= __shfl_xor(fl, s);
        if (lane == 0 && fl) atomicOr(&s_flags, fl);
    }

    // ---- fill-forward scan over chunk summaries ----
    unsigned int inc = summary;
    #pragma unroll
    for (int st = 1; st < 64; st <<= 1) {
        unsigned int o = __shfl_up(inc, st);
        if (lane >= st && !(inc & 4u)) inc = o;
    }
    unsigned int exc = __shfl_up(inc, 1);
    if (lane == 0) exc = 0u;
    if (lane == 63) s_wave[wid] = inc;
    __syncthreads();   // B
    if (wid == 0) {
        unsigned int wv = (lane < 16) ? s_wave[lane] : 0u;
        #pragma unroll
        for (int st = 1; st < 16; st <<= 1) {
            unsigned int o = __shfl_up(wv, st);
            if (lane >= st && !(wv & 4u)) wv = o;
        }
        unsigned int wex = __shfl_up(wv, 1);
        if (lane == 0) wex = 0u;
        if (lane < 16) s_wavex[lane] = wex;
    }
    __syncthreads();   // C

    unsigned int pre = (exc & 4u) ? exc : s_wavex[wid];
    int pm = (int)(pre & 1u), tm = (int)((pre >> 1) & 1u);
    const unsigned int flags = s_flags;
    const bool hasT2 = flags & 1u, hasP2 = flags & 2u;
    const bool hasT3 = flags & 4u, hasP3 = flags & 8u;

    // ---- Phase 3: replay with carry; merged window lookups; b128 ce reads ----
    float4 c0 = *(const float4*)(s_ce + base);
    float4 c1 = *(const float4*)(s_ce + base + 4);
    float cearr[8] = {c0.x, c0.y, c0.z, c0.w, c1.x, c1.y, c1.z, c1.w};

    float acc = 0.0f;
    #pragma unroll
    for (int i = 0; i < CHUNK; ++i) {
        int t = base + i;
        unsigned int pk = (unsigned int)(pkw >> (8 * i)) & 31u;
        int pred = pk & 3, l = (pk >> 2) & 3;
        bool valid = (pk & 16) != 0;
        float m = 1.0f;
        if (valid) {
            bool bad = (pred == 2 && pm == 0) || (pred == 3 && pm == 1);
            if (bad) m *= 100.0f;
            bool good = (l == 2 && tm == 1 && pred == 2) ||
                        (l == 3 && tm == 0 && pred == 3);
            if (good) m *= 0.1f;
            pm = pred & 1;
            tm = l & 1;
        }
        if (pred >= 2) {                       // predicted-switch multiplier
            bool has = (pred == 2) ? hasT2 : hasT3;
            if (!has) m *= 20.0f;
            else {
                int d = win_dist(s_m[(pred - 2) << 1], t);
                m *= (d == 0) ? 0.1f : (d <= 5) ? decay_pow(d) : 10.0f;
            }
        }
        if (valid && l >= 2) {                 // true-switch multiplier
            bool has = (l == 2) ? hasP2 : hasP3;
            if (!has) m *= 3.0f;
            else if (win_dist(s_m[1 + ((l - 2) << 1)], t) > 5) m *= 2.0f;
        }
        acc += cearr[i] * m;
    }

    // ---- Reduce to per-row partial ----
    double dacc = (double)acc;
    #pragma unroll
    for (int o = 32; o > 0; o >>= 1) {
        dacc += __shfl_down(dacc, o);
        cnt  += __shfl_down(cnt, o);
    }
    if (lane == 0) { s_red[wid] = dacc; s_redc[wid] = cnt; }
    __syncthreads();   // D
    if (tid == 0) {
        double tot = 0.0; unsigned int c = 0;
        #pragma unroll
        for (int i = 0; i < 16; ++i) { tot += s_red[i]; c += (unsigned int)s_redc[i]; }
        psum[row] = tot;
        pcnt[row] = c;
    }
}

__global__ __launch_bounds__(512) void finalize_kernel(
    const double* __restrict__ psum, const unsigned int* __restrict__ pcnt,
    float* __restrict__ out)
{
    __shared__ double       sd[8];
    __shared__ unsigned int sc[8];
    int tid = threadIdx.x, lane = tid & 63, wid = tid >> 6;
    double v = psum[tid];
    unsigned int c = pcnt[tid];
    #pragma unroll
    for (int o = 32; o > 0; o >>= 1) {
        v += __shfl_down(v, o);
        c += __shfl_down(c, o);
    }
    if (lane == 0) { sd[wid] = v; sc[wid] = c; }
    __syncthreads();
    if (tid == 0) {
        double t = 0.0; unsigned int cc = 0;
        #pragma unroll
        for (int i = 0; i < 8; ++i) { t += sd[i]; cc += sc[i]; }
        double d = (cc > 0u) ? (double)cc : 1.0;
        out[0] = (float)(t / d);
    }
}

extern "C" void kernel_launch(void* const* d_in, const int* in_sizes, int n_in,
                              void* d_out, int out_size, void* d_ws, size_t ws_size,
                              hipStream_t stream) {
    const float* logits = (const float*)d_in[0];
    const int*   labels = (const int*)d_in[1];
    float* out = (float*)d_out;
    double* psum = (double*)d_ws;
    unsigned int* pcnt = (unsigned int*)(psum + BROWS);

    row_loss_kernel<<<BROWS, NT, 0, stream>>>(logits, labels, psum, pcnt);
    finalize_kernel<<<1, 512, 0, stream>>>(psum, pcnt, out);
}